// Round 1
// baseline (60912.177 us; speedup 1.0000x reference)
//
#include <hip/hip_runtime.h>
#include <hip/hip_fp16.h>
#include <cstdio>
#include <cstdint>

#define T_STEPS 2048
#define BATCH   32
#define FEAT    512
#define HID     512
#define GATES   2048   // 4*HID
#define NWG_L   64     // workgroups per layer
#define NWG_TOT 128
#define ROUNDS  2049   // T_STEPS + 1 (layer pipeline)
#define ANCH    64

typedef __attribute__((ext_vector_type(8))) _Float16 half8;
typedef __attribute__((ext_vector_type(4))) float    f32x4;

// ---------------- workspace layout (bytes) ----------------
static const size_t SZ_WPACK = (size_t)2 * NWG_L * 2 * 32 * 64 * 8 * 2; // 8 MB fp16 fragment-packed [layer][wg][ntile][kk][lane][8]
static const size_t OFF_WFCP = SZ_WPACK;
static const size_t SZ_WFCP  = (size_t)4 * 16 * 64 * 8 * 2;             // 64 KB Wfc fragments [ntile4][kk16][lane][8]
static const size_t OFF_SYNC = OFF_WFCP + SZ_WFCP;
static const size_t SZ_SYNC  = 256;                                      // barrier counter
static const size_t OFF_HBC  = OFF_SYNC + SZ_SYNC;
static const size_t SZ_HBC   = (size_t)2 * 2 * BATCH * HID * 2;          // h broadcast [layer][parity][32][512] fp16
static const size_t OFF_H1S  = OFF_HBC + SZ_HBC;
static const size_t SZ_H1S   = (size_t)T_STEPS * BATCH * HID * 2;        // 64 MB h1 sequence fp16
static const size_t WS_NEEDED = OFF_H1S + SZ_H1S;                        // ~72.2 MB

// ---------------- weight fragment packing ----------------
// Layer weights W = [Wih; Whh] (K=1024 x 2048). Each layer-WG owns 32 gate cols:
// local col n = gate*8 + jj  ->  global col = gate*512 + wg*8 + jj.
// Fragment for (ntile, kk): lane holds B[k = kk*32 + (lane>>4)*8 + j, col = ntile*16 + (lane&15)], j=0..7.
__global__ void prep_pack(const float* __restrict__ Wih0, const float* __restrict__ Whh0,
                          const float* __restrict__ Wih1, const float* __restrict__ Whh1,
                          const float* __restrict__ Wfc,
                          _Float16* __restrict__ wpack, _Float16* __restrict__ wfcp) {
  int gid = blockIdx.x * 256 + threadIdx.x;
  const int NLT = 2 * NWG_L * 2 * 32 * 64;  // 524288 lane-tasks
  if (gid < NLT) {
    int lane  = gid & 63;
    int kk    = (gid >> 6) & 31;
    int nt    = (gid >> 11) & 1;
    int wg    = (gid >> 12) & 63;
    int layer = gid >> 18;
    int n   = nt * 16 + (lane & 15);
    int col = (n >> 3) * HID + wg * 8 + (n & 7);
    int kbase = kk * 32 + (lane >> 4) * 8;
    const float* Wih = layer ? Wih1 : Wih0;
    const float* Whh = layer ? Whh1 : Whh0;
    half8 v;
#pragma unroll
    for (int j = 0; j < 8; ++j) {
      int k = kbase + j;
      float f = (k < FEAT) ? Wih[(size_t)k * GATES + col]
                           : Whh[(size_t)(k - FEAT) * GATES + col];
      v[j] = (_Float16)f;
    }
    *(half8*)(wpack + (size_t)gid * 8) = v;
  } else {
    int fid = gid - NLT;
    if (fid < 4 * 16 * 64) {
      int lane = fid & 63;
      int kk   = (fid >> 6) & 15;
      int nt   = fid >> 10;
      int col  = nt * 16 + (lane & 15);
      int kbase = kk * 32 + (lane >> 4) * 8;
      half8 v;
#pragma unroll
      for (int j = 0; j < 8; ++j)
        v[j] = (_Float16)Wfc[(size_t)(kbase + j) * ANCH + col];
      *(half8*)(wfcp + (size_t)fid * 8) = v;
    }
  }
}

// ---------------- persistent layer-pipelined LSTM ----------------
// Grid = 128 WGs x 256 thr (1 WG/CU). WG 0..63 = layer0, 64..127 = layer1.
// Round r: L0 computes t=r (r<2048); L1 computes t=r-1 (r>=1).
// h broadcast double-buffered by parity: writers use r&1, readers (r-1)&1.
// LDS: Ash 32x1032 fp16 (66048 B) | wsh 2*32*64*8 fp16 (65536 B) | gsh 32x33 f32 (4224 B)
__global__ __launch_bounds__(256, 1) void lstm_persist(
    const float* __restrict__ x, const int* __restrict__ length,
    const float* __restrict__ b0v, const float* __restrict__ b1v,
    const _Float16* __restrict__ wpack,
    _Float16* __restrict__ h_bc, _Float16* __restrict__ h1_seq,
    unsigned int* cnt) {
  extern __shared__ char smem[];
  _Float16* Ash = (_Float16*)smem;
  _Float16* wsh = (_Float16*)(smem + 66048);
  float*    gsh = (float*)(smem + 66048 + 65536);

  const int tid   = threadIdx.x;
  const int wgid  = blockIdx.x;
  const int layer = wgid >> 6;
  const int wg    = wgid & 63;
  const int col0  = wg << 3;

  // weights -> LDS (resident for all steps)
  {
    const _Float16* src = wpack + (size_t)(layer * NWG_L + wg) * (2 * 32 * 64 * 8);
    for (int i = tid; i < 2 * 32 * 64; i += 256)
      *(half8*)(wsh + (size_t)i * 8) = *(const half8*)(src + (size_t)i * 8);
  }

  // per-thread cell state: thread (bb, jj) owns (batch bb, hidden col0+jj)
  const int bb = tid >> 3;
  const int jj = tid & 7;
  const float* bl = layer ? b1v : b0v;
  const float bias_f = bl[0 * HID + col0 + jj];
  const float bias_i = bl[1 * HID + col0 + jj];
  const float bias_o = bl[2 * HID + col0 + jj];
  const float bias_g = bl[3 * HID + col0 + jj];
  const int len = length[bb];
  float h_reg = 0.f, c_reg = 0.f;

  // MFMA ids: wave wv -> C quadrant (mtile, ntile) of the 32x32 gate tile
  const int wv = tid >> 6;
  const int lane = tid & 63;
  const int mtile = wv & 1, ntile = wv >> 1;
  const int arow = mtile * 16 + (lane & 15);
  const int koff = (lane >> 4) << 3;

  __syncthreads();

  for (int r = 0; r < ROUNDS; ++r) {
    const bool active = (layer == 0) ? (r < T_STEPS) : (r >= 1);
    if (active) {
      const int t = (layer == 0) ? r : (r - 1);
      const int par_r = (r - 1) & 1;
      const int par_w = r & 1;
      const _Float16* hsrc = h_bc + (size_t)(layer * 2 + par_r) * (BATCH * HID);
      // stage A = [x_t | h_prev] into LDS (fp16), row stride 1032 (bank-safe)
      if (layer == 0) {
        const float* xs = x + (size_t)t * (BATCH * FEAT);
        for (int i = tid; i < (BATCH * FEAT) / 8; i += 256) {
          int row = i >> 6, c8 = i & 63;
          const float* s = xs + row * FEAT + c8 * 8;
          float4 f0 = *(const float4*)(s);
          float4 f1 = *(const float4*)(s + 4);
          half8 v;
          v[0] = (_Float16)f0.x; v[1] = (_Float16)f0.y; v[2] = (_Float16)f0.z; v[3] = (_Float16)f0.w;
          v[4] = (_Float16)f1.x; v[5] = (_Float16)f1.y; v[6] = (_Float16)f1.z; v[7] = (_Float16)f1.w;
          *(half8*)(Ash + row * 1032 + c8 * 8) = v;
        }
      } else {
        const _Float16* xs = h_bc + (size_t)par_r * (BATCH * HID);  // layer0's h = our input
        for (int i = tid; i < (BATCH * HID) / 8; i += 256) {
          int row = i >> 6, c8 = i & 63;
          *(half8*)(Ash + row * 1032 + c8 * 8) = *(const half8*)(xs + row * HID + c8 * 8);
        }
      }
      for (int i = tid; i < (BATCH * HID) / 8; i += 256) {
        int row = i >> 6, c8 = i & 63;
        *(half8*)(Ash + row * 1032 + 512 + c8 * 8) = *(const half8*)(hsrc + row * HID + c8 * 8);
      }
      __syncthreads();

      // gates(32x32) = A(32x1024) . Wslice(1024x32), fp16 MFMA, fp32 accum
      f32x4 acc = {0.f, 0.f, 0.f, 0.f};
#pragma unroll 8
      for (int kk = 0; kk < 32; ++kk) {
        half8 av = *(const half8*)(Ash + arow * 1032 + kk * 32 + koff);
        half8 bv = *(const half8*)(wsh + ((ntile * 32 + kk) * 64 + lane) * 8);
        acc = __builtin_amdgcn_mfma_f32_16x16x32_f16(av, bv, acc, 0, 0, 0);
      }
      {
        int crow = mtile * 16 + ((lane >> 4) << 2);
        int ccol = ntile * 16 + (lane & 15);
#pragma unroll
        for (int q = 0; q < 4; ++q) gsh[(crow + q) * 33 + ccol] = acc[q];
      }
      __syncthreads();

      // nonlinearity + length-masked state update (fp32, local)
      {
        float fg = gsh[bb * 33 + 0  + jj] + bias_f;
        float ig = gsh[bb * 33 + 8  + jj] + bias_i;
        float og = gsh[bb * 33 + 16 + jj] + bias_o;
        float gg = gsh[bb * 33 + 24 + jj] + bias_g;
        float sf = 1.f / (1.f + expf(-fg));
        float si = 1.f / (1.f + expf(-ig));
        float so = 1.f / (1.f + expf(-og));
        float c1 = sf * c_reg + si * tanhf(gg);
        float h1 = so * tanhf(c1);
        if (t < len) { c_reg = c1; h_reg = h1; }
        h_bc[(size_t)(layer * 2 + par_w) * (BATCH * HID) + bb * HID + col0 + jj] = (_Float16)h_reg;
        if (layer == 1)
          h1_seq[((size_t)t * BATCH + bb) * HID + col0 + jj] = (_Float16)h_reg;
      }
    }
    // ---- device-wide barrier (agent-scope; XCD-safe) ----
    __threadfence();                 // release: own stores visible device-wide
    __syncthreads();
    if (tid == 0) {
      __hip_atomic_fetch_add(cnt, 1u, __ATOMIC_ACQ_REL, __HIP_MEMORY_SCOPE_AGENT);
      const unsigned tgt = (unsigned)(r + 1) * NWG_TOT;
      int guard = 0;
      while (__hip_atomic_load(cnt, __ATOMIC_RELAXED, __HIP_MEMORY_SCOPE_AGENT) < tgt) {
        __builtin_amdgcn_s_sleep(1);
        if (++guard > (1 << 24)) break;   // fail loud (wrong answer), never hang
      }
    }
    __syncthreads();
    __threadfence();                 // acquire: invalidate stale L1/L2 before reads
  }
}

// ---------------- final FC: out[t] = h1[t] @ Wfc + bfc ----------------
// One block per timestep; C = (32 x 64), K = 512. 4 waves: (mtile, ntile-pair).
__global__ __launch_bounds__(256) void fc_gemm(
    const _Float16* __restrict__ h1_seq, const _Float16* __restrict__ wfcp,
    const float* __restrict__ bfc, float* __restrict__ out) {
  const int bt  = blockIdx.x;
  const int tid = threadIdx.x;
  const int wv = tid >> 6, lane = tid & 63;
  const int mtile = wv & 1, npair = wv >> 1;
  const int arow = mtile * 16 + (lane & 15);
  const int koff = (lane >> 4) << 3;
  const _Float16* A = h1_seq + (size_t)bt * (BATCH * HID);
  f32x4 acc0 = {0.f, 0.f, 0.f, 0.f}, acc1 = {0.f, 0.f, 0.f, 0.f};
#pragma unroll 4
  for (int kk = 0; kk < 16; ++kk) {
    half8 av = *(const half8*)(A + arow * HID + kk * 32 + koff);
    half8 bv0 = *(const half8*)(wfcp + (((npair * 2 + 0) * 16 + kk) * 64 + lane) * 8);
    half8 bv1 = *(const half8*)(wfcp + (((npair * 2 + 1) * 16 + kk) * 64 + lane) * 8);
    acc0 = __builtin_amdgcn_mfma_f32_16x16x32_f16(av, bv0, acc0, 0, 0, 0);
    acc1 = __builtin_amdgcn_mfma_f32_16x16x32_f16(av, bv1, acc1, 0, 0, 0);
  }
  const int crow = mtile * 16 + ((lane >> 4) << 2);
  const int c0 = (npair * 2 + 0) * 16 + (lane & 15);
  const int c1 = (npair * 2 + 1) * 16 + (lane & 15);
  const float bc0 = bfc[c0], bc1 = bfc[c1];
#pragma unroll
  for (int q = 0; q < 4; ++q) {
    int b = crow + q;
    out[((size_t)bt * BATCH + b) * ANCH + c0] = acc0[q] + bc0;
    out[((size_t)bt * BATCH + b) * ANCH + c1] = acc1[q] + bc1;
  }
}

// ---------------- host ----------------
extern "C" void kernel_launch(void* const* d_in, const int* in_sizes, int n_in,
                              void* d_out, int out_size, void* d_ws, size_t ws_size,
                              hipStream_t stream) {
  const float* x    = (const float*)d_in[0];
  const int*   len  = (const int*)  d_in[1];
  const float* Wih0 = (const float*)d_in[2];
  const float* Whh0 = (const float*)d_in[3];
  const float* b0   = (const float*)d_in[4];
  const float* Wih1 = (const float*)d_in[5];
  const float* Whh1 = (const float*)d_in[6];
  const float* b1   = (const float*)d_in[7];
  const float* Wfc  = (const float*)d_in[8];
  const float* bfc  = (const float*)d_in[9];
  float* out = (float*)d_out;
  char* ws = (char*)d_ws;
  (void)in_sizes; (void)n_in; (void)out_size;

  if (ws_size < WS_NEEDED) {
    fprintf(stderr, "kernel_launch: ws_size %zu < needed %zu\n", ws_size, WS_NEEDED);
    return;
  }

  _Float16* wpack = (_Float16*)(ws);
  _Float16* wfcp  = (_Float16*)(ws + OFF_WFCP);
  unsigned int* cnt = (unsigned int*)(ws + OFF_SYNC);
  _Float16* h_bc  = (_Float16*)(ws + OFF_HBC);
  _Float16* h1s   = (_Float16*)(ws + OFF_H1S);

  // zero barrier counter + h broadcast buffers (ws is poisoned 0xAA each call)
  hipMemsetAsync(ws + OFF_SYNC, 0, SZ_SYNC + SZ_HBC, stream);

  prep_pack<<<2064, 256, 0, stream>>>(Wih0, Whh0, Wih1, Whh1, Wfc, wpack, wfcp);

  hipFuncSetAttribute((const void*)lstm_persist,
                      hipFuncAttributeMaxDynamicSharedMemorySize, 135808);
  lstm_persist<<<NWG_TOT, 256, 135808, stream>>>(x, len, b0, b1, wpack, h_bc, h1s, cnt);

  fc_gemm<<<T_STEPS, 256, 0, stream>>>(h1s, wfcp, bfc, out);
}

// Round 4
// 24077.673 us; speedup vs baseline: 2.5298x; 2.5298x over previous
//
#include <hip/hip_runtime.h>
#include <hip/hip_fp16.h>
#include <cstdio>
#include <cstdint>

#define T_STEPS 2048
#define BATCH   32
#define FEAT    512
#define HID     512
#define GATES   2048   // 4*HID
#define NWG_L   64     // workgroups per layer
#define NWG_TOT 128
#define ROUNDS  2049   // T_STEPS + 1 (layer pipeline)
#define ANCH    64

typedef __attribute__((ext_vector_type(8))) _Float16 half8;
typedef __attribute__((ext_vector_type(4))) _Float16 half4;
typedef __attribute__((ext_vector_type(4))) float    f32x4;

// ---------------- workspace layout (bytes) ----------------
static const size_t SZ_WPACK = (size_t)2 * NWG_L * 2 * 32 * 64 * 8 * 2; // 8 MB fp16 fragment-packed
static const size_t OFF_WFCP = SZ_WPACK;
static const size_t SZ_WFCP  = (size_t)4 * 16 * 64 * 8 * 2;             // 64 KB Wfc fragments
static const size_t OFF_SYNC = OFF_WFCP + SZ_WFCP;
static const size_t SZ_SYNC  = 256;                                      // barrier counter
static const size_t OFF_HBC  = OFF_SYNC + SZ_SYNC;
static const size_t SZ_HBC   = (size_t)4 * 8192 * 4;                     // h broadcast u32[layer][parity][32][256] (fp16 pairs)
static const size_t OFF_H1S  = OFF_HBC + SZ_HBC;
static const size_t SZ_H1S   = (size_t)T_STEPS * BATCH * HID * 2;        // 64 MB h1 sequence fp16
static const size_t WS_NEEDED = OFF_H1S + SZ_H1S;                        // ~72.2 MB

// ---------------- weight fragment packing + state zeroing ----------------
__global__ void prep_pack(const float* __restrict__ Wih0, const float* __restrict__ Whh0,
                          const float* __restrict__ Wih1, const float* __restrict__ Whh1,
                          const float* __restrict__ Wfc,
                          _Float16* __restrict__ wpack, _Float16* __restrict__ wfcp,
                          unsigned int* __restrict__ h_bc, unsigned int* __restrict__ cnt) {
  int gid = blockIdx.x * 256 + threadIdx.x;
  const int NLT = 2 * NWG_L * 2 * 32 * 64;  // 524288 lane-tasks
  if (gid < NLT) {
    int lane  = gid & 63;
    int kk    = (gid >> 6) & 31;
    int nt    = (gid >> 11) & 1;
    int wg    = (gid >> 12) & 63;
    int layer = gid >> 18;
    int n   = nt * 16 + (lane & 15);
    int col = (n >> 3) * HID + wg * 8 + (n & 7);
    int kbase = kk * 32 + (lane >> 4) * 8;
    const float* Wih = layer ? Wih1 : Wih0;
    const float* Whh = layer ? Whh1 : Whh0;
    half8 v;
#pragma unroll
    for (int j = 0; j < 8; ++j) {
      int k = kbase + j;
      float f = (k < FEAT) ? Wih[(size_t)k * GATES + col]
                           : Whh[(size_t)(k - FEAT) * GATES + col];
      v[j] = (_Float16)f;
    }
    *(half8*)(wpack + (size_t)gid * 8) = v;
  } else if (gid < NLT + 4 * 16 * 64) {
    int fid = gid - NLT;
    int lane = fid & 63;
    int kk   = (fid >> 6) & 15;
    int nt   = fid >> 10;
    int col  = nt * 16 + (lane & 15);
    int kbase = kk * 32 + (lane >> 4) * 8;
    half8 v;
#pragma unroll
    for (int j = 0; j < 8; ++j)
      v[j] = (_Float16)Wfc[(size_t)(kbase + j) * ANCH + col];
    *(half8*)(wfcp + (size_t)fid * 8) = v;
  } else {
    // zero h broadcast buffers + barrier counter with AGENT-scope (write-through)
    // stores so lstm_persist's cache-bypassing loads see them on every XCD.
    int zid = gid - (NLT + 4 * 16 * 64);
    if (zid >= 0 && zid < 4 * 8192) {
      __hip_atomic_store(h_bc + zid, 0u, __ATOMIC_RELAXED, __HIP_MEMORY_SCOPE_AGENT);
    } else if (zid == 4 * 8192) {
      __hip_atomic_store(cnt, 0u, __ATOMIC_RELAXED, __HIP_MEMORY_SCOPE_AGENT);
    }
  }
}

// ---------------- persistent layer-pipelined LSTM ----------------
// 128 WGs x 256 thr (1 WG/CU). WG 0..63 = layer0, 64..127 = layer1.
// Round r: L0 computes t=r (r<2048); L1 computes t=r-1 (r>=1).
// Cross-WG h traffic via relaxed agent-scope atomics (coherence-point
// write-through / cache-bypass) -> no buffer_inv / threadfence anywhere.
// LDS: Ash 32x1032 fp16 (66048 B) | wsh 2*32*64*8 fp16 (65536 B) | gsh 32x33 f32 (4224 B)
__global__ __launch_bounds__(256, 1) void lstm_persist(
    const float* __restrict__ x, const int* __restrict__ length,
    const float* __restrict__ b0v, const float* __restrict__ b1v,
    const _Float16* __restrict__ wpack,
    unsigned int* __restrict__ h_bc, _Float16* __restrict__ h1_seq,
    unsigned int* cnt) {
  extern __shared__ char smem[];
  _Float16* Ash = (_Float16*)smem;
  _Float16* wsh = (_Float16*)(smem + 66048);
  float*    gsh = (float*)(smem + 66048 + 65536);

  const int tid   = threadIdx.x;
  const int wgid  = blockIdx.x;
  const int layer = wgid >> 6;
  const int wg    = wgid & 63;
  const int col0  = wg << 3;

  // weights -> LDS (resident for all steps)
  {
    const _Float16* src = wpack + (size_t)(layer * NWG_L + wg) * (2 * 32 * 64 * 8);
    for (int i = tid; i < 2 * 32 * 64; i += 256)
      *(half8*)(wsh + (size_t)i * 8) = *(const half8*)(src + (size_t)i * 8);
  }

  // per-thread cell state: thread (bb, jj) owns (batch bb, hidden col0+jj)
  const int bb = tid >> 3;
  const int jj = tid & 7;
  const float* bl = layer ? b1v : b0v;
  const float bias_f = bl[0 * HID + col0 + jj];
  const float bias_i = bl[1 * HID + col0 + jj];
  const float bias_o = bl[2 * HID + col0 + jj];
  const float bias_g = bl[3 * HID + col0 + jj];
  const int len = length[bb];
  float h_reg = 0.f, c_reg = 0.f;

  // MFMA ids: wave wv -> C quadrant (mtile, ntile) of the 32x32 gate tile
  const int wv = tid >> 6;
  const int lane = tid & 63;
  const int mtile = wv & 1, ntile = wv >> 1;
  const int arow = mtile * 16 + (lane & 15);
  const int koff = (lane >> 4) << 3;

  __syncthreads();

  for (int r = 0; r < ROUNDS; ++r) {
    const bool active = (layer == 0) ? (r < T_STEPS) : (r >= 1);
    const int t = (layer == 0) ? r : (r - 1);
    const int par_r = (r - 1) & 1;
    const int par_w = r & 1;

    f32x4 acc = {0.f, 0.f, 0.f, 0.f};

    // ---- pre-barrier work: stage x_t and run the x-part MFMAs (L0 only) ----
    if (active && layer == 0) {
      const float* xs = x + (size_t)t * (BATCH * FEAT);
      for (int i = tid; i < (BATCH * FEAT) / 8; i += 256) {
        int row = i >> 6, c8 = i & 63;
        const float* s = xs + row * FEAT + c8 * 8;
        float4 f0 = *(const float4*)(s);
        float4 f1 = *(const float4*)(s + 4);
        half8 v;
        v[0] = (_Float16)f0.x; v[1] = (_Float16)f0.y; v[2] = (_Float16)f0.z; v[3] = (_Float16)f0.w;
        v[4] = (_Float16)f1.x; v[5] = (_Float16)f1.y; v[6] = (_Float16)f1.z; v[7] = (_Float16)f1.w;
        *(half8*)(Ash + row * 1032 + c8 * 8) = v;
      }
      __syncthreads();
#pragma unroll
      for (int kk = 0; kk < 16; ++kk) {
        half8 av = *(const half8*)(Ash + arow * 1032 + kk * 32 + koff);
        half8 bv = *(const half8*)(wsh + ((ntile * 32 + kk) * 64 + lane) * 8);
        acc = __builtin_amdgcn_mfma_f32_16x16x32_f16(av, bv, acc, 0, 0, 0);
      }
    }

    // ---- strict-phase global barrier wait (ALL WGs, incl. inactive) ----
    if (r > 0) {
      if (tid == 0) {
        const unsigned tgt = (unsigned)r * NWG_TOT;
        int guard = 0;
        while (__hip_atomic_load(cnt, __ATOMIC_RELAXED, __HIP_MEMORY_SCOPE_AGENT) < tgt) {
          __builtin_amdgcn_s_sleep(1);
          if (++guard > (1 << 20)) break;   // fail loud (wrong answer), never hang
        }
      }
      __syncthreads();
    }

    if (active) {
      // ---- stage h parts via coherence-point loads (bypass stale L1/L2) ----
      {
        const unsigned long long* own =
            (const unsigned long long*)(h_bc + (size_t)(layer * 2 + par_r) * 8192);
        for (int i = tid; i < 4096; i += 256) {
          int row = i >> 7, c4 = i & 127;
          unsigned long long v =
              __hip_atomic_load(own + i, __ATOMIC_RELAXED, __HIP_MEMORY_SCOPE_AGENT);
          *(half4*)(Ash + row * 1032 + 512 + c4 * 4) = __builtin_bit_cast(half4, v);
        }
        if (layer == 1) {
          const unsigned long long* inp =
              (const unsigned long long*)(h_bc + (size_t)par_r * 8192);  // layer0 slot
          for (int i = tid; i < 4096; i += 256) {
            int row = i >> 7, c4 = i & 127;
            unsigned long long v =
                __hip_atomic_load(inp + i, __ATOMIC_RELAXED, __HIP_MEMORY_SCOPE_AGENT);
            *(half4*)(Ash + row * 1032 + c4 * 4) = __builtin_bit_cast(half4, v);
          }
        }
      }
      __syncthreads();

      // ---- remaining MFMAs (L0: h-part only; L1: full K) ----
      const int kk0 = (layer == 0) ? 16 : 0;
#pragma unroll 8
      for (int kk = kk0; kk < 32; ++kk) {
        half8 av = *(const half8*)(Ash + arow * 1032 + kk * 32 + koff);
        half8 bv = *(const half8*)(wsh + ((ntile * 32 + kk) * 64 + lane) * 8);
        acc = __builtin_amdgcn_mfma_f32_16x16x32_f16(av, bv, acc, 0, 0, 0);
      }
      {
        int crow = mtile * 16 + ((lane >> 4) << 2);
        int ccol = ntile * 16 + (lane & 15);
#pragma unroll
        for (int q = 0; q < 4; ++q) gsh[(crow + q) * 33 + ccol] = acc[q];
      }
      __syncthreads();

      // ---- nonlinearity + length-masked state update (fp32, local) ----
      {
        float fg = gsh[bb * 33 + 0  + jj] + bias_f;
        float ig = gsh[bb * 33 + 8  + jj] + bias_i;
        float og = gsh[bb * 33 + 16 + jj] + bias_o;
        float gg = gsh[bb * 33 + 24 + jj] + bias_g;
        float sf = 1.f / (1.f + expf(-fg));
        float si = 1.f / (1.f + expf(-ig));
        float so = 1.f / (1.f + expf(-og));
        float c1 = sf * c_reg + si * tanhf(gg);
        float h1 = so * tanhf(c1);
        if (t < len) { c_reg = c1; h_reg = h1; }

        _Float16 hf = (_Float16)h_reg;
        unsigned hb = (unsigned)__builtin_bit_cast(unsigned short, hf);
        unsigned nb = (unsigned)__shfl_down((int)hb, 1);
        if ((jj & 1) == 0) {
          unsigned pack = hb | (nb << 16);
          __hip_atomic_store(h_bc + (size_t)(layer * 2 + par_w) * 8192 + bb * 256 + ((col0 + jj) >> 1),
                             pack, __ATOMIC_RELAXED, __HIP_MEMORY_SCOPE_AGENT);
        }
        if (layer == 1)
          h1_seq[((size_t)t * BATCH + bb) * HID + col0 + jj] = hf;
      }
    }

    // ---- arrive: syncthreads drains vmcnt(0) for every wave's stores,
    //      then one RELEASE add per WG (no buffer_inv anywhere) ----
    __syncthreads();
    if (tid == 0)
      __hip_atomic_fetch_add(cnt, 1u, __ATOMIC_RELEASE, __HIP_MEMORY_SCOPE_AGENT);
  }
}

// ---------------- final FC: out[t] = h1[t] @ Wfc + bfc ----------------
__global__ __launch_bounds__(256) void fc_gemm(
    const _Float16* __restrict__ h1_seq, const _Float16* __restrict__ wfcp,
    const float* __restrict__ bfc, float* __restrict__ out) {
  const int bt  = blockIdx.x;
  const int tid = threadIdx.x;
  const int wv = tid >> 6, lane = tid & 63;
  const int mtile = wv & 1, npair = wv >> 1;
  const int arow = mtile * 16 + (lane & 15);
  const int koff = (lane >> 4) << 3;
  const _Float16* A = h1_seq + (size_t)bt * (BATCH * HID);
  f32x4 acc0 = {0.f, 0.f, 0.f, 0.f}, acc1 = {0.f, 0.f, 0.f, 0.f};
#pragma unroll 4
  for (int kk = 0; kk < 16; ++kk) {
    half8 av = *(const half8*)(A + arow * HID + kk * 32 + koff);
    half8 bv0 = *(const half8*)(wfcp + (((npair * 2 + 0) * 16 + kk) * 64 + lane) * 8);
    half8 bv1 = *(const half8*)(wfcp + (((npair * 2 + 1) * 16 + kk) * 64 + lane) * 8);
    acc0 = __builtin_amdgcn_mfma_f32_16x16x32_f16(av, bv0, acc0, 0, 0, 0);
    acc1 = __builtin_amdgcn_mfma_f32_16x16x32_f16(av, bv1, acc1, 0, 0, 0);
  }
  const int crow = mtile * 16 + ((lane >> 4) << 2);
  const int c0 = (npair * 2 + 0) * 16 + (lane & 15);
  const int c1 = (npair * 2 + 1) * 16 + (lane & 15);
  const float bc0 = bfc[c0], bc1 = bfc[c1];
#pragma unroll
  for (int q = 0; q < 4; ++q) {
    int b = crow + q;
    out[((size_t)bt * BATCH + b) * ANCH + c0] = acc0[q] + bc0;
    out[((size_t)bt * BATCH + b) * ANCH + c1] = acc1[q] + bc1;
  }
}

// ---------------- host ----------------
extern "C" void kernel_launch(void* const* d_in, const int* in_sizes, int n_in,
                              void* d_out, int out_size, void* d_ws, size_t ws_size,
                              hipStream_t stream) {
  const float* x    = (const float*)d_in[0];
  const int*   len  = (const int*)  d_in[1];
  const float* Wih0 = (const float*)d_in[2];
  const float* Whh0 = (const float*)d_in[3];
  const float* b0   = (const float*)d_in[4];
  const float* Wih1 = (const float*)d_in[5];
  const float* Whh1 = (const float*)d_in[6];
  const float* b1   = (const float*)d_in[7];
  const float* Wfc  = (const float*)d_in[8];
  const float* bfc  = (const float*)d_in[9];
  float* out = (float*)d_out;
  char* ws = (char*)d_ws;
  (void)in_sizes; (void)n_in; (void)out_size;

  if (ws_size < WS_NEEDED) {
    fprintf(stderr, "kernel_launch: ws_size %zu < needed %zu\n", ws_size, WS_NEEDED);
    return;
  }

  _Float16* wpack = (_Float16*)(ws);
  _Float16* wfcp  = (_Float16*)(ws + OFF_WFCP);
  unsigned int* cnt = (unsigned int*)(ws + OFF_SYNC);
  unsigned int* h_bc = (unsigned int*)(ws + OFF_HBC);
  _Float16* h1s   = (_Float16*)(ws + OFF_H1S);

  // 524288 + 4096 + 32768 + 1 = 561153 tasks -> 2193 blocks
  prep_pack<<<2193, 256, 0, stream>>>(Wih0, Whh0, Wih1, Whh1, Wfc, wpack, wfcp, h_bc, cnt);

  hipFuncSetAttribute((const void*)lstm_persist,
                      hipFuncAttributeMaxDynamicSharedMemorySize, 135808);
  lstm_persist<<<NWG_TOT, 256, 135808, stream>>>(x, len, b0, b1, wpack, h_bc, h1s, cnt);

  fc_gemm<<<T_STEPS, 256, 0, stream>>>(h1s, wfcp, bfc, out);
}